// Round 6
// baseline (358.323 us; speedup 1.0000x reference)
//
#include <hip/hip_runtime.h>
#include <hip/hip_fp16.h>
#include <math.h>

#define NH 4        // heads
#define DD 64       // out features per head
#define NF 256      // NH*DD
#define KF 128      // in features
#define NN 4096     // nodes
#define NB 2        // batch
#define NG 8        // NB*NH groups
#define CH 32       // scan chunk length
#define NCH 128     // NN / CH
#define SUB 8       // elements per wave within a chunk (4 waves * 8 = CH)

// ---------------- Kernel 1: H = X @ W  (fp32 math, fp16 H store), fused s/d epilogue ----------------
__global__ __launch_bounds__(256) void k_gemm(const float* __restrict__ X,
                                              const float* __restrict__ W,
                                              const float* __restrict__ a_src,
                                              const float* __restrict__ a_dst,
                                              __half* __restrict__ Hout,
                                              float* __restrict__ s_arr,
                                              float* __restrict__ d_arr) {
  __shared__ float As[64][132];
  const int bm = blockIdx.x;               // 0..127
  const int bn = blockIdx.y;               // 0..3 (head)
  const int tid = threadIdx.x;

  for (int i = tid; i < 64 * 32; i += 256) {
    int r = i >> 5, c4 = i & 31;
    float4 v = *(const float4*)(X + ((size_t)(bm * 64 + r)) * KF + c4 * 4);
    *(float4*)&As[r][c4 * 4] = v;
  }
  __syncthreads();

  const int ty = tid >> 4, tx = tid & 15;
  const int col0 = bn * 64 + tx * 4;
  const float* Wp = W + col0;              // stride NF
  float acc[4][4] = {{0.f}};

  #pragma unroll 2
  for (int k4 = 0; k4 < 32; ++k4) {
    float4 a[4];
    #pragma unroll
    for (int i = 0; i < 4; ++i) a[i] = *(const float4*)&As[ty * 4 + i][k4 * 4];
    #pragma unroll
    for (int jk = 0; jk < 4; ++jk) {
      float4 b = *(const float4*)(Wp + (size_t)(k4 * 4 + jk) * NF);
      #pragma unroll
      for (int i = 0; i < 4; ++i) {
        float av = ((const float*)&a[i])[jk];
        acc[i][0] += av * b.x;
        acc[i][1] += av * b.y;
        acc[i][2] += av * b.z;
        acc[i][3] += av * b.w;
      }
    }
  }

  const float4 asv = *(const float4*)(a_src + bn * 64 + tx * 4);
  const float4 adv = *(const float4*)(a_dst + bn * 64 + tx * 4);
  const int grow0 = bm * 64 + ty * 4;
  #pragma unroll
  for (int i = 0; i < 4; ++i) {
    int grow = grow0 + i;
    union { __half2 h2[2]; float2 f2; } u;
    u.h2[0] = __floats2half2_rn(acc[i][0], acc[i][1]);
    u.h2[1] = __floats2half2_rn(acc[i][2], acc[i][3]);
    *(float2*)&Hout[(size_t)grow * NF + col0] = u.f2;
    float ps = acc[i][0] * asv.x + acc[i][1] * asv.y + acc[i][2] * asv.z + acc[i][3] * asv.w;
    float pd = acc[i][0] * adv.x + acc[i][1] * adv.y + acc[i][2] * adv.z + acc[i][3] * adv.w;
    #pragma unroll
    for (int off = 1; off < 16; off <<= 1) {
      ps += __shfl_xor(ps, off);
      pd += __shfl_xor(pd, off);
    }
    if (tx == 0) {
      int b = grow >> 12, n = grow & (NN - 1);
      int g = b * NH + bn;
      s_arr[g * NN + n] = ps;
      d_arr[g * NN + n] = pd;
    }
  }
}

// ---------------- Kernel 2: per-(b,h) bitonic sort, 4-consecutive ownership ----------------
// also zeroes the fused kernel's barrier counters (runs strictly before it on the stream)
__global__ __launch_bounds__(1024) void k_sort(const float* __restrict__ d_arr,
                                               float* __restrict__ dsort,
                                               int* __restrict__ perm,
                                               int* __restrict__ cnt1,
                                               int* __restrict__ cnt2) {
  __shared__ float4 skey[1024];
  __shared__ int4 sidx[1024];
  const int g = blockIdx.x;
  const int tid = threadIdx.x;
  if (tid == 0) { cnt1[g] = 0; cnt2[g] = 0; }

  float kk[4];
  int ii[4];
  {
    float4 kv = *(const float4*)(d_arr + g * NN + 4 * tid);
    kk[0] = kv.x; kk[1] = kv.y; kk[2] = kv.z; kk[3] = kv.w;
    ii[0] = 4 * tid; ii[1] = 4 * tid + 1; ii[2] = 4 * tid + 2; ii[3] = 4 * tid + 3;
  }

  #define CE(a, b, asc)                                            \
    do { if ((kk[a] > kk[b]) == (asc)) {                           \
      float tk = kk[a]; kk[a] = kk[b]; kk[b] = tk;                 \
      int ti = ii[a]; ii[a] = ii[b]; ii[b] = ti; } } while (0)

  CE(0, 1, true);
  CE(2, 3, false);

  #pragma unroll
  for (int k = 4; k <= NN; k <<= 1) {
    const bool asc = (tid & (k >> 2)) == 0;
    #pragma unroll
    for (int j = k >> 1; j > 0; j >>= 1) {
      if (j >= 256) {
        const int tdist = j >> 2;
        skey[tid] = make_float4(kk[0], kk[1], kk[2], kk[3]);
        sidx[tid] = make_int4(ii[0], ii[1], ii[2], ii[3]);
        __syncthreads();
        float4 pk4 = skey[tid ^ tdist];
        int4 pi4 = sidx[tid ^ tdist];
        const bool lower = (tid & tdist) == 0;
        #pragma unroll
        for (int r = 0; r < 4; ++r) {
          float pk = (&pk4.x)[r];
          int pid = (&pi4.x)[r];
          float kl = lower ? kk[r] : pk;
          float kh = lower ? pk : kk[r];
          if ((kl > kh) == asc) { kk[r] = pk; ii[r] = pid; }
        }
        __syncthreads();
      } else if (j >= 4) {
        const int dist = j >> 2;
        const bool lower = (tid & dist) == 0;
        #pragma unroll
        for (int r = 0; r < 4; ++r) {
          float pk = __shfl_xor(kk[r], dist);
          int pid = __shfl_xor(ii[r], dist);
          float kl = lower ? kk[r] : pk;
          float kh = lower ? pk : kk[r];
          if ((kl > kh) == asc) { kk[r] = pk; ii[r] = pid; }
        }
      } else if (j == 2) {
        CE(0, 2, asc);
        CE(1, 3, asc);
      } else {
        CE(0, 1, asc);
        CE(2, 3, asc);
      }
    }
  }
  #undef CE

  *(float4*)(dsort + g * NN + 4 * tid) = make_float4(kk[0], kk[1], kk[2], kk[3]);
  *(int4*)(perm + g * NN + 4 * tid) = make_int4(ii[0], ii[1], ii[2], ii[3]);
}

// per-group software barrier: 128 blocks of group g rendezvous on cnt[g]
__device__ __forceinline__ void group_barrier(int* cnt) {
  __syncthreads();
  if (threadIdx.x == 0) {
    __threadfence();                       // release: publish prior global writes
    atomicAdd(cnt, 1);
    while (__hip_atomic_load(cnt, __ATOMIC_RELAXED, __HIP_MEMORY_SCOPE_AGENT) < NCH) {
      __builtin_amdgcn_s_sleep(8);
    }
  }
  __syncthreads();
  __threadfence();                         // acquire: invalidate before reading others' data
}

// ---------------- Kernel 3 (fused): scan phases A/B + output phase C, per-group barriers ----------------
__global__ __launch_bounds__(256, 4) void k_fused(const __half* __restrict__ Hmat,
                                                  const float* __restrict__ dsort,
                                                  const int* __restrict__ perm,
                                                  const float* __restrict__ s_arr,
                                                  float* __restrict__ chunkP, float* __restrict__ chunkS,
                                                  float* __restrict__ chunkPw, float* __restrict__ chunkSw,
                                                  __half* __restrict__ Ph, __half* __restrict__ Sh,
                                                  float* __restrict__ Pexp, float* __restrict__ Sexp,
                                                  const float* __restrict__ bias,
                                                  float* __restrict__ out,
                                                  int* cnt1, int* cnt2) {
  __shared__ float subP[4][64], subS[4][64];
  __shared__ float subPw[4], subSw[4];
  __shared__ float ppart[4][64], spart[4][64];

  const int blk = blockIdx.x;   // 0..1023
  const int ch = blk & 127;
  const int g = blk >> 7;
  const int b = g >> 2, h = g & 3;
  const int c = threadIdx.x & 63;
  const int w = threadIdx.x >> 6;
  const int gNN = g * NN;
  const size_t bNN = (size_t)b * NN;
  const int h64 = h * 64;
  const float dmax = dsort[gNN + NN - 1];
  const int kw0 = ch * CH + w * SUB;

  // ===== Phase A: batched loads + sub-chunk sums (registers persist into phase B) =====
  int j8[SUB]; float d8[SUB], hv8[SUB], wp8[SUB], ws8[SUB];
  #pragma unroll
  for (int l = 0; l < SUB; ++l) j8[l] = perm[gNN + kw0 + l];
  #pragma unroll
  for (int l = 0; l < SUB; ++l) d8[l] = dsort[gNN + kw0 + l];
  #pragma unroll
  for (int l = 0; l < SUB; ++l) hv8[l] = __half2float(Hmat[(bNN + j8[l]) * NF + h64 + c]);

  float pa = 0.f, sa = 0.f, pwl = 0.f, swl = 0.f;
  #pragma unroll
  for (int l = 0; l < SUB; ++l) {
    wp8[l] = __expf(0.2f * (d8[l] - dmax));
    ws8[l] = __expf(d8[l] - dmax);
    pa += wp8[l] * hv8[l]; sa += ws8[l] * hv8[l];
    pwl += wp8[l]; swl += ws8[l];
  }
  subP[w][c] = pa; subS[w][c] = sa;
  if (c == 0) { subPw[w] = pwl; subSw[w] = swl; }
  __syncthreads();

  if (w == 0) {
    float tp = subP[0][c] + subP[1][c] + subP[2][c] + subP[3][c];
    float ts = subS[0][c] + subS[1][c] + subS[2][c] + subS[3][c];
    chunkP[(g * NCH + ch) * 64 + c] = tp;
    chunkS[(g * NCH + ch) * 64 + c] = ts;
    if (c == 0) {
      chunkPw[g * NCH + ch] = subPw[0] + subPw[1] + subPw[2] + subPw[3];
      chunkSw[g * NCH + ch] = subSw[0] + subSw[1] + subSw[2] + subSw[3];
    }
  }

  group_barrier(cnt1 + g);

  // ===== Phase B: cross-chunk offsets + register replay, write Ph/Sh/Pexp/Sexp =====
  float pp = 0.f, sp = 0.f;
  for (int t = w; t < ch; t += 4)            pp += chunkP[(g * NCH + t) * 64 + c];
  for (int t = ch + 1 + w; t < NCH; t += 4)  sp += chunkS[(g * NCH + t) * 64 + c];
  ppart[w][c] = pp; spart[w][c] = sp;

  float w1 = chunkPw[g * NCH + c];
  float w2 = chunkPw[g * NCH + 64 + c];
  float pwo = (c < ch ? w1 : 0.f) + (c + 64 < ch ? w2 : 0.f);
  float u1 = chunkSw[g * NCH + c];
  float u2 = chunkSw[g * NCH + 64 + c];
  float swo = (c > ch ? u1 : 0.f) + (c + 64 > ch ? u2 : 0.f);
  #pragma unroll
  for (int off = 1; off < 64; off <<= 1) {
    pwo += __shfl_xor(pwo, off);
    swo += __shfl_xor(swo, off);
  }

  __syncthreads();

  float poffv = ppart[0][c] + ppart[1][c] + ppart[2][c] + ppart[3][c];
  float soffv = spart[0][c] + spart[1][c] + spart[2][c] + spart[3][c];
  float intraP = 0.f, intraS = 0.f, intraPw = 0.f, intraSw = 0.f;
  #pragma unroll
  for (int t = 0; t < 4; ++t) {
    if (t < w) { intraP += subP[t][c]; intraPw += subPw[t]; }
    if (t > w) { intraS += subS[t][c]; intraSw += subSw[t]; }
  }

  float rp = poffv + intraP, rw = pwo + intraPw;
  #pragma unroll
  for (int l = 0; l < SUB; ++l) {
    int k = kw0 + l;
    rp += wp8[l] * hv8[l]; rw += wp8[l];
    Ph[((size_t)(gNN + k)) * 64 + c] = __float2half(rp);
    if (c == 0) Pexp[gNN + k] = rw;
  }
  float rs = soffv + intraS, rsw = swo + intraSw;
  #pragma unroll
  for (int l = SUB - 1; l >= 0; --l) {
    int k = kw0 + l;
    rs += ws8[l] * hv8[l]; rsw += ws8[l];
    Sh[((size_t)(gNN + k)) * 64 + c] = __float2half(rs);
    if (c == 0) Sexp[gNN + k] = rsw;
  }

  group_barrier(cnt2 + g);

  // ===== Phase C: per-row combine + bias + ELU (8 rows per wave, batched ILP) =====
  const int lane = c;
  const int i0 = ch * CH + w * 8;              // 8 consecutive rows of group g
  const float* ds = dsort + (size_t)g * NN;
  const float biasv = bias[h64 + lane];

  float si8[8];
  #pragma unroll
  for (int l = 0; l < 8; ++l) si8[l] = s_arr[gNN + i0 + l];

  const float probe1 = ds[lane * 64 + 63];     // shared across the 8 rows
  int b1[8];
  #pragma unroll
  for (int l = 0; l < 8; ++l) {
    unsigned long long m1 = __ballot(probe1 <= -si8[l]);
    b1[l] = __popcll(m1);
  }
  float probe2[8];
  #pragma unroll
  for (int l = 0; l < 8; ++l)
    probe2[l] = (b1[l] < 64) ? ds[b1[l] * 64 + lane] : 0.f;
  int m8[8];
  #pragma unroll
  for (int l = 0; l < 8; ++l) {
    if (b1[l] == 64) m8[l] = NN;
    else {
      unsigned long long m2 = __ballot(probe2[l] <= -si8[l]);
      m8[l] = b1[l] * 64 + __popcll(m2);
    }
  }

  float numA[8], denA[8], numB[8], denB[8];
  #pragma unroll
  for (int l = 0; l < 8; ++l) {
    int m = m8[l];
    if (m < NN) {
      numA[l] = __half2float(Sh[((size_t)(gNN + m)) * 64 + lane]);
      denA[l] = Sexp[gNN + m];
    } else { numA[l] = 0.f; denA[l] = 0.f; }
    if (m > 0) {
      numB[l] = __half2float(Ph[((size_t)(gNN + m - 1)) * 64 + lane]);
      denB[l] = Pexp[gNN + m - 1];
    } else { numB[l] = 0.f; denB[l] = 0.f; }
  }

  #pragma unroll
  for (int l = 0; l < 8; ++l) {
    const float sdm = si8[l] + dmax;
    const float mx = sdm > 0.f ? sdm : 0.2f * sdm;
    const float alpha = __expf(sdm - mx);
    const float beta = __expf(0.2f * sdm - mx);
    const float den = alpha * denA[l] + beta * denB[l];
    float val = (alpha * numA[l] + beta * numB[l]) / den + biasv;
    float o = val > 0.f ? val : expm1f(val);
    out[((size_t)(bNN + i0 + l)) * NF + h64 + lane] = o;
  }
}

extern "C" void kernel_launch(void* const* d_in, const int* in_sizes, int n_in,
                              void* d_out, int out_size, void* d_ws, size_t ws_size,
                              hipStream_t stream) {
  const float* X = (const float*)d_in[0];       // [2,4096,128]
  const float* W = (const float*)d_in[1];       // [128,256]
  const float* a_src = (const float*)d_in[2];   // [4,64,1]
  const float* a_dst = (const float*)d_in[3];   // [4,64,1]
  const float* bias = (const float*)d_in[4];    // [256]
  float* out = (float*)d_out;                   // [2,4096,256]

  float* ws = (float*)d_ws;
  float* s_arr = ws;                    // 8*4096
  float* d_arr = s_arr + NG * NN;       // 8*4096
  float* dsort = d_arr + NG * NN;       // 8*4096
  int* perm = (int*)(dsort + NG * NN);  // 8*4096
  float* Pexp = (float*)(perm + NG * NN);
  float* Sexp = Pexp + NG * NN;
  float* chunkP = Sexp + NG * NN;       // 8*128*64
  float* chunkS = chunkP + NG * NCH * 64;
  float* chunkPw = chunkS + NG * NCH * 64;  // 8*128
  float* chunkSw = chunkPw + NG * NCH;
  int* cnt1 = (int*)(chunkSw + NG * NCH);   // 8 ints
  int* cnt2 = cnt1 + NG;                    // 8 ints
  __half* Hmat = (__half*)(cnt2 + NG + 48); // 2*4096*256 halves (4 MB), padded to 16B align
  __half* Ph = Hmat + (size_t)NB * NN * NF; // 8*4096*64 halves
  __half* Sh = Ph + (size_t)NG * NN * 64;

  k_gemm<<<dim3(128, 4), 256, 0, stream>>>(X, W, a_src, a_dst, Hmat, s_arr, d_arr);
  k_sort<<<NG, 1024, 0, stream>>>(d_arr, dsort, perm, cnt1, cnt2);
  k_fused<<<1024, 256, 0, stream>>>(Hmat, dsort, perm, s_arr,
                                    chunkP, chunkS, chunkPw, chunkSw,
                                    Ph, Sh, Pexp, Sexp, bias, out, cnt1, cnt2);
}

// Round 7
// 74.318 us; speedup vs baseline: 4.8215x; 4.8215x over previous
//
#include <hip/hip_runtime.h>
#include <hip/hip_fp16.h>
#include <math.h>

#define NH 4        // heads
#define DD 64       // out features per head
#define NF 256      // NH*DD
#define KF 128      // in features
#define NN 4096     // nodes
#define NB 2        // batch
#define NG 8        // NB*NH groups
#define CH 32       // scan chunk length
#define NCH 128     // NN / CH
#define SUB 8       // elements per wave within a chunk (4 waves * 8 = CH)

// ---------------- Kernel 1: H = X @ W  (fp32 math, fp16 H store), fused s/d epilogue ----------------
__global__ __launch_bounds__(256) void k_gemm(const float* __restrict__ X,
                                              const float* __restrict__ W,
                                              const float* __restrict__ a_src,
                                              const float* __restrict__ a_dst,
                                              __half* __restrict__ Hout,
                                              float* __restrict__ s_arr,
                                              float* __restrict__ d_arr) {
  __shared__ float As[64][132];
  const int bm = blockIdx.x;               // 0..127
  const int bn = blockIdx.y;               // 0..3 (head)
  const int tid = threadIdx.x;

  for (int i = tid; i < 64 * 32; i += 256) {
    int r = i >> 5, c4 = i & 31;
    float4 v = *(const float4*)(X + ((size_t)(bm * 64 + r)) * KF + c4 * 4);
    *(float4*)&As[r][c4 * 4] = v;
  }
  __syncthreads();

  const int ty = tid >> 4, tx = tid & 15;
  const int col0 = bn * 64 + tx * 4;
  const float* Wp = W + col0;              // stride NF
  float acc[4][4] = {{0.f}};

  #pragma unroll 2
  for (int k4 = 0; k4 < 32; ++k4) {
    float4 a[4];
    #pragma unroll
    for (int i = 0; i < 4; ++i) a[i] = *(const float4*)&As[ty * 4 + i][k4 * 4];
    #pragma unroll
    for (int jk = 0; jk < 4; ++jk) {
      float4 b = *(const float4*)(Wp + (size_t)(k4 * 4 + jk) * NF);
      #pragma unroll
      for (int i = 0; i < 4; ++i) {
        float av = ((const float*)&a[i])[jk];
        acc[i][0] += av * b.x;
        acc[i][1] += av * b.y;
        acc[i][2] += av * b.z;
        acc[i][3] += av * b.w;
      }
    }
  }

  const float4 asv = *(const float4*)(a_src + bn * 64 + tx * 4);
  const float4 adv = *(const float4*)(a_dst + bn * 64 + tx * 4);
  const int grow0 = bm * 64 + ty * 4;
  #pragma unroll
  for (int i = 0; i < 4; ++i) {
    int grow = grow0 + i;
    union { __half2 h2[2]; float2 f2; } u;
    u.h2[0] = __floats2half2_rn(acc[i][0], acc[i][1]);
    u.h2[1] = __floats2half2_rn(acc[i][2], acc[i][3]);
    *(float2*)&Hout[(size_t)grow * NF + col0] = u.f2;
    float ps = acc[i][0] * asv.x + acc[i][1] * asv.y + acc[i][2] * asv.z + acc[i][3] * asv.w;
    float pd = acc[i][0] * adv.x + acc[i][1] * adv.y + acc[i][2] * adv.z + acc[i][3] * adv.w;
    #pragma unroll
    for (int off = 1; off < 16; off <<= 1) {
      ps += __shfl_xor(ps, off);
      pd += __shfl_xor(pd, off);
    }
    if (tx == 0) {
      int b = grow >> 12, n = grow & (NN - 1);
      int g = b * NH + bn;
      s_arr[g * NN + n] = ps;
      d_arr[g * NN + n] = pd;
    }
  }
}

// ---------------- Kernel 2: bitonic sort, 4-consecutive ownership ----------------
// blocks 0..7: sort d ascending -> (dsort, dperm). blocks 8..15: sort t = -s ascending -> (tsort, tperm)
__global__ __launch_bounds__(1024) void k_sort(const float* __restrict__ d_arr,
                                               const float* __restrict__ s_arr,
                                               float* __restrict__ dsort, int* __restrict__ dperm,
                                               float* __restrict__ tsort, int* __restrict__ tperm) {
  __shared__ float4 skey[1024];
  __shared__ int4 sidx[1024];
  const int bid = blockIdx.x;
  const bool isT = bid >= NG;
  const int g = isT ? bid - NG : bid;
  const float* src = isT ? s_arr : d_arr;
  float* okey = isT ? tsort : dsort;
  int* operm = isT ? tperm : dperm;
  const int tid = threadIdx.x;

  float kk[4];
  int ii[4];
  {
    float4 kv = *(const float4*)(src + g * NN + 4 * tid);
    kk[0] = kv.x; kk[1] = kv.y; kk[2] = kv.z; kk[3] = kv.w;
    if (isT) { kk[0] = -kk[0]; kk[1] = -kk[1]; kk[2] = -kk[2]; kk[3] = -kk[3]; }
    ii[0] = 4 * tid; ii[1] = 4 * tid + 1; ii[2] = 4 * tid + 2; ii[3] = 4 * tid + 3;
  }

  #define CE(a, b, asc)                                            \
    do { if ((kk[a] > kk[b]) == (asc)) {                           \
      float tk = kk[a]; kk[a] = kk[b]; kk[b] = tk;                 \
      int ti = ii[a]; ii[a] = ii[b]; ii[b] = ti; } } while (0)

  CE(0, 1, true);
  CE(2, 3, false);

  #pragma unroll
  for (int k = 4; k <= NN; k <<= 1) {
    const bool asc = (tid & (k >> 2)) == 0;
    #pragma unroll
    for (int j = k >> 1; j > 0; j >>= 1) {
      if (j >= 256) {
        const int tdist = j >> 2;
        skey[tid] = make_float4(kk[0], kk[1], kk[2], kk[3]);
        sidx[tid] = make_int4(ii[0], ii[1], ii[2], ii[3]);
        __syncthreads();
        float4 pk4 = skey[tid ^ tdist];
        int4 pi4 = sidx[tid ^ tdist];
        const bool lower = (tid & tdist) == 0;
        #pragma unroll
        for (int r = 0; r < 4; ++r) {
          float pk = (&pk4.x)[r];
          int pid = (&pi4.x)[r];
          float kl = lower ? kk[r] : pk;
          float kh = lower ? pk : kk[r];
          if ((kl > kh) == asc) { kk[r] = pk; ii[r] = pid; }
        }
        __syncthreads();
      } else if (j >= 4) {
        const int dist = j >> 2;
        const bool lower = (tid & dist) == 0;
        #pragma unroll
        for (int r = 0; r < 4; ++r) {
          float pk = __shfl_xor(kk[r], dist);
          int pid = __shfl_xor(ii[r], dist);
          float kl = lower ? kk[r] : pk;
          float kh = lower ? pk : kk[r];
          if ((kl > kh) == asc) { kk[r] = pk; ii[r] = pid; }
        }
      } else if (j == 2) {
        CE(0, 2, asc);
        CE(1, 3, asc);
      } else {
        CE(0, 1, asc);
        CE(2, 3, asc);
      }
    }
  }
  #undef CE

  *(float4*)(okey + g * NN + 4 * tid) = make_float4(kk[0], kk[1], kk[2], kk[3]);
  *(int4*)(operm + g * NN + 4 * tid) = make_int4(ii[0], ii[1], ii[2], ii[3]);
}

// ---------------- Kernel 3: per-chunk partial sums ----------------
__global__ __launch_bounds__(256) void k_part(const __half* __restrict__ Hmat,
                                              const float* __restrict__ dsort,
                                              const int* __restrict__ dperm,
                                              float* __restrict__ chunkP, float* __restrict__ chunkS,
                                              float* __restrict__ chunkPw, float* __restrict__ chunkSw) {
  __shared__ float subP[4][64], subS[4][64];
  __shared__ float subPw[4], subSw[4];
  const int ch = blockIdx.x;   // 0..127
  const int g = blockIdx.y;    // 0..7
  const int b = g >> 2, h = g & 3;
  const int c = threadIdx.x & 63;
  const int w = threadIdx.x >> 6;
  const int gNN = g * NN;
  const size_t bNN = (size_t)b * NN;
  const int h64 = h * 64;
  const float dmax = dsort[gNN + NN - 1];
  const int kw0 = ch * CH + w * SUB;

  int j8[SUB]; float d8[SUB], hv8[SUB];
  #pragma unroll
  for (int l = 0; l < SUB; ++l) j8[l] = dperm[gNN + kw0 + l];
  #pragma unroll
  for (int l = 0; l < SUB; ++l) d8[l] = dsort[gNN + kw0 + l];
  #pragma unroll
  for (int l = 0; l < SUB; ++l) hv8[l] = __half2float(Hmat[(bNN + j8[l]) * NF + h64 + c]);

  float pa = 0.f, sa = 0.f, pw = 0.f, sw = 0.f;
  #pragma unroll
  for (int l = 0; l < SUB; ++l) {
    float wp = __expf(0.2f * (d8[l] - dmax));
    float ws = __expf(d8[l] - dmax);
    pa += wp * hv8[l]; sa += ws * hv8[l]; pw += wp; sw += ws;
  }
  subP[w][c] = pa; subS[w][c] = sa;
  if (c == 0) { subPw[w] = pw; subSw[w] = sw; }
  __syncthreads();

  if (w == 0) {
    float tp = subP[0][c] + subP[1][c] + subP[2][c] + subP[3][c];
    float ts = subS[0][c] + subS[1][c] + subS[2][c] + subS[3][c];
    chunkP[(g * NCH + ch) * 64 + c] = tp;
    chunkS[(g * NCH + ch) * 64 + c] = ts;
    if (c == 0) {
      chunkPw[g * NCH + ch] = subPw[0] + subPw[1] + subPw[2] + subPw[3];
      chunkSw[g * NCH + ch] = subSw[0] + subSw[1] + subSw[2] + subSw[3];
    }
  }
}

// ---------------- Kernel 4: serve rows from local chunk prefixes (replaces k_fin + k_out) ----------------
// block (g,ch): rebuild chunk ch's 33-entry inclusive prefix tables (both weight types) in LDS,
// binary-search the t-sorted rows whose rank m-1 falls in this chunk, serve each row:
//   P(m-1) = chunk offsets + local prefix;  S(m) = totS - PS(m-1)
__global__ __launch_bounds__(256, 4) void k_serve(const __half* __restrict__ Hmat,
                                                  const float* __restrict__ dsort,
                                                  const int* __restrict__ dperm,
                                                  const float* __restrict__ tsort,
                                                  const int* __restrict__ tperm,
                                                  const float* __restrict__ chunkP, const float* __restrict__ chunkS,
                                                  const float* __restrict__ chunkPw, const float* __restrict__ chunkSw,
                                                  const float* __restrict__ bias,
                                                  float* __restrict__ out) {
  __shared__ float PPloc[CH + 1][64], PSloc[CH + 1][64];
  __shared__ float ppwLoc[CH + 1], pswLoc[CH + 1];
  __shared__ float subP[4][64], subS[4][64], sall[4][64];
  __shared__ float subPw[4], subSw[4];

  const int ch = blockIdx.x & (NCH - 1);
  const int g = blockIdx.x >> 7;
  const int b = g >> 2, h = g & 3;
  const int c = threadIdx.x & 63;
  const int w = threadIdx.x >> 6;
  const int gNN = g * NN;
  const size_t bNN = (size_t)b * NN;
  const int h64 = h * 64;
  const float dmax = dsort[gNN + NN - 1];
  const int kw0 = ch * CH + w * SUB;

  // --- phase 1: gather chunk H, weights, intra-sub inclusive prefixes ---
  int j8[SUB]; float d8[SUB], hv8[SUB];
  #pragma unroll
  for (int l = 0; l < SUB; ++l) j8[l] = dperm[gNN + kw0 + l];
  #pragma unroll
  for (int l = 0; l < SUB; ++l) d8[l] = dsort[gNN + kw0 + l];
  #pragma unroll
  for (int l = 0; l < SUB; ++l) hv8[l] = __half2float(Hmat[(bNN + j8[l]) * NF + h64 + c]);

  float ppv[SUB], psv[SUB], ppw[SUB], psw[SUB];
  {
    float ap = 0.f, as = 0.f, aw = 0.f, aswv = 0.f;
    #pragma unroll
    for (int l = 0; l < SUB; ++l) {
      float wp = __expf(0.2f * (d8[l] - dmax));
      float ws = __expf(d8[l] - dmax);
      ap += wp * hv8[l]; as += ws * hv8[l]; aw += wp; aswv += ws;
      ppv[l] = ap; psv[l] = as; ppw[l] = aw; psw[l] = aswv;
    }
    subP[w][c] = ap; subS[w][c] = as;
    if (c == 0) { subPw[w] = aw; subSw[w] = aswv; }
  }
  __syncthreads();

  // --- phase 2: add earlier-subchunk offsets, publish local prefix tables ---
  {
    float oP = 0.f, oS = 0.f, oPw = 0.f, oSw = 0.f;
    #pragma unroll
    for (int t = 0; t < 4; ++t) {
      if (t < w) { oP += subP[t][c]; oS += subS[t][c]; oPw += subPw[t]; oSw += subSw[t]; }
    }
    #pragma unroll
    for (int l = 0; l < SUB; ++l) {
      PPloc[w * SUB + 1 + l][c] = ppv[l] + oP;
      PSloc[w * SUB + 1 + l][c] = psv[l] + oS;
    }
    if (c == 0) {
      #pragma unroll
      for (int l = 0; l < SUB; ++l) {
        ppwLoc[w * SUB + 1 + l] = ppw[l] + oPw;
        pswLoc[w * SUB + 1 + l] = psw[l] + oSw;
      }
    }
    if (w == 0) {
      PPloc[0][c] = 0.f; PSloc[0][c] = 0.f;
      if (c == 0) { ppwLoc[0] = 0.f; pswLoc[0] = 0.f; }
    }
  }
  __syncthreads();

  // --- phase 3: cross-chunk channel offsets (prefix < ch) + total S, split over waves ---
  {
    float pp = 0.f, sp = 0.f, sa = 0.f;
    for (int t = w; t < ch; t += 4) pp += chunkP[(g * NCH + t) * 64 + c];
    for (int t = w; t < NCH; t += 4) {
      float v = chunkS[(g * NCH + t) * 64 + c];
      sa += v;
      if (t < ch) sp += v;
    }
    subP[w][c] = pp; subS[w][c] = sp; sall[w][c] = sa;
  }

  // scalar chunk offsets: lane-parallel + wave reduce (redundant per wave, cheap)
  float offPw, offSw, totSw;
  {
    float w1 = chunkPw[g * NCH + c];
    float w2 = chunkPw[g * NCH + 64 + c];
    float pwo = (c < ch ? w1 : 0.f) + (c + 64 < ch ? w2 : 0.f);
    float u1 = chunkSw[g * NCH + c];
    float u2 = chunkSw[g * NCH + 64 + c];
    float swo = (c < ch ? u1 : 0.f) + (c + 64 < ch ? u2 : 0.f);
    float stw = u1 + u2;
    #pragma unroll
    for (int off = 1; off < 64; off <<= 1) {
      pwo += __shfl_xor(pwo, off);
      swo += __shfl_xor(swo, off);
      stw += __shfl_xor(stw, off);
    }
    offPw = pwo; offSw = swo; totSw = stw;
  }
  __syncthreads();

  const float offP = subP[0][c] + subP[1][c] + subP[2][c] + subP[3][c];
  const float offS = subS[0][c] + subS[1][c] + subS[2][c] + subS[3][c];
  const float totS = sall[0][c] + sall[1][c] + sall[2][c] + sall[3][c];

  // --- phase 4: row range via binary search on t-sorted keys ---
  const float* ts = tsort + gNN;
  int rlo, rhi;
  {
    float blo = dsort[gNN + ch * CH];
    if (ch == 0) rlo = 0;
    else {
      int lo = 0, hi = NN;
      while (lo < hi) { int mid = (lo + hi) >> 1; if (ts[mid] < blo) lo = mid + 1; else hi = mid; }
      rlo = lo;
    }
    if (ch == NCH - 1) rhi = NN;
    else {
      float bhi = dsort[gNN + (ch + 1) * CH];
      int lo = 0, hi = NN;
      while (lo < hi) { int mid = (lo + hi) >> 1; if (ts[mid] < bhi) lo = mid + 1; else hi = mid; }
      rhi = lo;
    }
  }

  // lane c<32 holds chunk d value for rank-in-chunk ballot
  const float myd = (c < 32) ? dsort[gNN + ch * CH + c] : __int_as_float(0x7f800000);
  const float biasv = bias[h64 + c];

  // --- phase 5: serve rows ---
  for (int r = rlo + w; r < rhi; r += 4) {
    const float t = ts[r];
    const int i = tperm[gNN + r];
    const int mloc = __popcll(__ballot(myd <= t));
    const float numB = PPloc[mloc][c] + offP;
    const float denB = ppwLoc[mloc] + offPw;
    const float numA = totS - (PSloc[mloc][c] + offS);
    const float denA = totSw - (pswLoc[mloc] + offSw);
    const float si = -t;
    const float sdm = si + dmax;
    const float mx = sdm > 0.f ? sdm : 0.2f * sdm;
    const float alpha = __expf(sdm - mx);
    const float beta = __expf(0.2f * sdm - mx);
    const float den = alpha * denA + beta * denB;
    float val = (alpha * numA + beta * numB) / den + biasv;
    float o = val > 0.f ? val : expm1f(val);
    out[(bNN + i) * NF + h64 + c] = o;
  }
}

extern "C" void kernel_launch(void* const* d_in, const int* in_sizes, int n_in,
                              void* d_out, int out_size, void* d_ws, size_t ws_size,
                              hipStream_t stream) {
  const float* X = (const float*)d_in[0];       // [2,4096,128]
  const float* W = (const float*)d_in[1];       // [128,256]
  const float* a_src = (const float*)d_in[2];   // [4,64,1]
  const float* a_dst = (const float*)d_in[3];   // [4,64,1]
  const float* bias = (const float*)d_in[4];    // [256]
  float* out = (float*)d_out;                   // [2,4096,256]

  float* ws = (float*)d_ws;
  float* s_arr = ws;                        // 8*4096
  float* d_arr = s_arr + NG * NN;           // 8*4096
  float* dsort = d_arr + NG * NN;           // 8*4096
  int* dperm = (int*)(dsort + NG * NN);     // 8*4096
  float* tsort = (float*)(dperm + NG * NN); // 8*4096
  int* tperm = (int*)(tsort + NG * NN);     // 8*4096
  float* chunkP = (float*)(tperm + NG * NN);    // 8*128*64
  float* chunkS = chunkP + NG * NCH * 64;
  float* chunkPw = chunkS + NG * NCH * 64;      // 8*128
  float* chunkSw = chunkPw + NG * NCH;
  __half* Hmat = (__half*)(chunkSw + NG * NCH); // 2*4096*256 halves (4 MB)

  k_gemm<<<dim3(128, 4), 256, 0, stream>>>(X, W, a_src, a_dst, Hmat, s_arr, d_arr);
  k_sort<<<2 * NG, 1024, 0, stream>>>(d_arr, s_arr, dsort, dperm, tsort, tperm);
  k_part<<<dim3(NCH, NG), 256, 0, stream>>>(Hmat, dsort, dperm, chunkP, chunkS, chunkPw, chunkSw);
  k_serve<<<NG * NCH, 256, 0, stream>>>(Hmat, dsort, dperm, tsort, tperm,
                                        chunkP, chunkS, chunkPw, chunkSw, bias, out);
}

// Round 8
// 69.515 us; speedup vs baseline: 5.1546x; 1.0691x over previous
//
#include <hip/hip_runtime.h>
#include <hip/hip_fp16.h>
#include <math.h>

#define NH 4        // heads
#define DD 64       // out features per head
#define NF 256      // NH*DD
#define KF 128      // in features
#define NN 4096     // nodes
#define NB 2        // batch
#define NG 8        // NB*NH groups
#define CH 32       // scan chunk length
#define NCH 128     // NN / CH
#define SUB 8       // elements per wave within a chunk (4 waves * 8 = CH)

typedef _Float16 h8_t __attribute__((ext_vector_type(8)));
typedef float f4_t __attribute__((ext_vector_type(4)));

// ---------------- Kernel 1: H = X @ W via fp16 MFMA (fp32 accum), fused s/d epilogue ----------------
// block: 64 rows x 64 cols (head bn); 4 waves, each 16 rows x 64 cols = 4 tiles x 4 K-steps.
__global__ __launch_bounds__(256) void k_gemm(const float* __restrict__ X,
                                              const float* __restrict__ W,
                                              const float* __restrict__ a_src,
                                              const float* __restrict__ a_dst,
                                              __half* __restrict__ Hout,
                                              float* __restrict__ s_arr,
                                              float* __restrict__ d_arr) {
  __shared__ float As[64][132];        // X tile, fp32 (row stride 132: 2-way conflicts only)
  __shared__ _Float16 WT[64][136];     // W block transposed [col][k] fp16 (b128-readable)
  const int bm = blockIdx.x;           // 0..127 row tile
  const int bn = blockIdx.y;           // 0..3 head
  const int tid = threadIdx.x;

  for (int i = tid; i < 64 * 32; i += 256) {
    int r = i >> 5, c4 = i & 31;
    float4 v = *(const float4*)(X + ((size_t)(bm * 64 + r)) * KF + c4 * 4);
    *(float4*)&As[r][c4 * 4] = v;
  }
  for (int i = tid; i < 64 * 128; i += 256) {
    int k = i >> 6, c = i & 63;
    WT[c][k] = (_Float16)W[(size_t)k * NF + bn * 64 + c];
  }
  __syncthreads();

  const int lane = tid & 63, w = tid >> 6;
  const int l15 = lane & 15, lq = lane >> 4;

  f4_t acc[4] = {f4_t{0.f,0.f,0.f,0.f}, f4_t{0.f,0.f,0.f,0.f},
                 f4_t{0.f,0.f,0.f,0.f}, f4_t{0.f,0.f,0.f,0.f}};

  #pragma unroll
  for (int kk = 0; kk < 4; ++kk) {
    const int koff = kk * 32 + lq * 8;
    h8_t a;
    {
      const float* ap = &As[w * 16 + l15][koff];
      float4 x0 = *(const float4*)ap;
      float4 x1 = *(const float4*)(ap + 4);
      a[0] = (_Float16)x0.x; a[1] = (_Float16)x0.y;
      a[2] = (_Float16)x0.z; a[3] = (_Float16)x0.w;
      a[4] = (_Float16)x1.x; a[5] = (_Float16)x1.y;
      a[6] = (_Float16)x1.z; a[7] = (_Float16)x1.w;
    }
    #pragma unroll
    for (int t = 0; t < 4; ++t) {
      h8_t b = *(const h8_t*)&WT[t * 16 + l15][koff];
      acc[t] = __builtin_amdgcn_mfma_f32_16x16x32_f16(a, b, acc[t], 0, 0, 0);
    }
  }

  // epilogue: D[m][n]: n = l15 (col within tile), m = lq*4 + j (row within 16)
  float asv[4], adv[4];
  #pragma unroll
  for (int t = 0; t < 4; ++t) {
    asv[t] = a_src[bn * 64 + t * 16 + l15];
    adv[t] = a_dst[bn * 64 + t * 16 + l15];
  }
  #pragma unroll
  for (int j = 0; j < 4; ++j) {
    const int grow = bm * 64 + w * 16 + lq * 4 + j;
    float ps = 0.f, pd = 0.f;
    #pragma unroll
    for (int t = 0; t < 4; ++t) {
      float hv = acc[t][j];
      Hout[(size_t)grow * NF + bn * 64 + t * 16 + l15] = __float2half(hv);
      ps += hv * asv[t];
      pd += hv * adv[t];
    }
    #pragma unroll
    for (int off = 1; off < 16; off <<= 1) {
      ps += __shfl_xor(ps, off);
      pd += __shfl_xor(pd, off);
    }
    if (l15 == 0) {
      int b = grow >> 12, n = grow & (NN - 1);
      int g = b * NH + bn;
      s_arr[g * NN + n] = ps;
      d_arr[g * NN + n] = pd;
    }
  }
}

// ---------------- Kernel 2: bitonic sort, 4-consecutive ownership ----------------
// blocks 0..7: sort d ascending -> (dsort, dperm). blocks 8..15: sort t = -s ascending -> (tsort, tperm)
__global__ __launch_bounds__(1024) void k_sort(const float* __restrict__ d_arr,
                                               const float* __restrict__ s_arr,
                                               float* __restrict__ dsort, int* __restrict__ dperm,
                                               float* __restrict__ tsort, int* __restrict__ tperm) {
  __shared__ float4 skey[1024];
  __shared__ int4 sidx[1024];
  const int bid = blockIdx.x;
  const bool isT = bid >= NG;
  const int g = isT ? bid - NG : bid;
  const float* src = isT ? s_arr : d_arr;
  float* okey = isT ? tsort : dsort;
  int* operm = isT ? tperm : dperm;
  const int tid = threadIdx.x;

  float kk[4];
  int ii[4];
  {
    float4 kv = *(const float4*)(src + g * NN + 4 * tid);
    kk[0] = kv.x; kk[1] = kv.y; kk[2] = kv.z; kk[3] = kv.w;
    if (isT) { kk[0] = -kk[0]; kk[1] = -kk[1]; kk[2] = -kk[2]; kk[3] = -kk[3]; }
    ii[0] = 4 * tid; ii[1] = 4 * tid + 1; ii[2] = 4 * tid + 2; ii[3] = 4 * tid + 3;
  }

  #define CE(a, b, asc)                                            \
    do { if ((kk[a] > kk[b]) == (asc)) {                           \
      float tk = kk[a]; kk[a] = kk[b]; kk[b] = tk;                 \
      int ti = ii[a]; ii[a] = ii[b]; ii[b] = ti; } } while (0)

  CE(0, 1, true);
  CE(2, 3, false);

  #pragma unroll
  for (int k = 4; k <= NN; k <<= 1) {
    const bool asc = (tid & (k >> 2)) == 0;
    #pragma unroll
    for (int j = k >> 1; j > 0; j >>= 1) {
      if (j >= 256) {
        const int tdist = j >> 2;
        skey[tid] = make_float4(kk[0], kk[1], kk[2], kk[3]);
        sidx[tid] = make_int4(ii[0], ii[1], ii[2], ii[3]);
        __syncthreads();
        float4 pk4 = skey[tid ^ tdist];
        int4 pi4 = sidx[tid ^ tdist];
        const bool lower = (tid & tdist) == 0;
        #pragma unroll
        for (int r = 0; r < 4; ++r) {
          float pk = (&pk4.x)[r];
          int pid = (&pi4.x)[r];
          float kl = lower ? kk[r] : pk;
          float kh = lower ? pk : kk[r];
          if ((kl > kh) == asc) { kk[r] = pk; ii[r] = pid; }
        }
        __syncthreads();
      } else if (j >= 4) {
        const int dist = j >> 2;
        const bool lower = (tid & dist) == 0;
        #pragma unroll
        for (int r = 0; r < 4; ++r) {
          float pk = __shfl_xor(kk[r], dist);
          int pid = __shfl_xor(ii[r], dist);
          float kl = lower ? kk[r] : pk;
          float kh = lower ? pk : kk[r];
          if ((kl > kh) == asc) { kk[r] = pk; ii[r] = pid; }
        }
      } else if (j == 2) {
        CE(0, 2, asc);
        CE(1, 3, asc);
      } else {
        CE(0, 1, asc);
        CE(2, 3, asc);
      }
    }
  }
  #undef CE

  *(float4*)(okey + g * NN + 4 * tid) = make_float4(kk[0], kk[1], kk[2], kk[3]);
  *(int4*)(operm + g * NN + 4 * tid) = make_int4(ii[0], ii[1], ii[2], ii[3]);
}

// ---------------- Kernel 3: per-chunk partial sums ----------------
__global__ __launch_bounds__(256) void k_part(const __half* __restrict__ Hmat,
                                              const float* __restrict__ dsort,
                                              const int* __restrict__ dperm,
                                              float* __restrict__ chunkP, float* __restrict__ chunkS,
                                              float* __restrict__ chunkPw, float* __restrict__ chunkSw) {
  __shared__ float subP[4][64], subS[4][64];
  __shared__ float subPw[4], subSw[4];
  const int ch = blockIdx.x;   // 0..127
  const int g = blockIdx.y;    // 0..7
  const int b = g >> 2, h = g & 3;
  const int c = threadIdx.x & 63;
  const int w = threadIdx.x >> 6;
  const int gNN = g * NN;
  const size_t bNN = (size_t)b * NN;
  const int h64 = h * 64;
  const float dmax = dsort[gNN + NN - 1];
  const int kw0 = ch * CH + w * SUB;

  int j8[SUB]; float d8[SUB], hv8[SUB];
  #pragma unroll
  for (int l = 0; l < SUB; ++l) j8[l] = dperm[gNN + kw0 + l];
  #pragma unroll
  for (int l = 0; l < SUB; ++l) d8[l] = dsort[gNN + kw0 + l];
  #pragma unroll
  for (int l = 0; l < SUB; ++l) hv8[l] = __half2float(Hmat[(bNN + j8[l]) * NF + h64 + c]);

  float pa = 0.f, sa = 0.f, pw = 0.f, sw = 0.f;
  #pragma unroll
  for (int l = 0; l < SUB; ++l) {
    float wp = __expf(0.2f * (d8[l] - dmax));
    float ws = __expf(d8[l] - dmax);
    pa += wp * hv8[l]; sa += ws * hv8[l]; pw += wp; sw += ws;
  }
  subP[w][c] = pa; subS[w][c] = sa;
  if (c == 0) { subPw[w] = pw; subSw[w] = sw; }
  __syncthreads();

  if (w == 0) {
    float tp = subP[0][c] + subP[1][c] + subP[2][c] + subP[3][c];
    float ts = subS[0][c] + subS[1][c] + subS[2][c] + subS[3][c];
    chunkP[(g * NCH + ch) * 64 + c] = tp;
    chunkS[(g * NCH + ch) * 64 + c] = ts;
    if (c == 0) {
      chunkPw[g * NCH + ch] = subPw[0] + subPw[1] + subPw[2] + subPw[3];
      chunkSw[g * NCH + ch] = subSw[0] + subSw[1] + subSw[2] + subSw[3];
    }
  }
}

// ---------------- Kernel 4: serve rows from local chunk prefixes ----------------
__global__ __launch_bounds__(256, 4) void k_serve(const __half* __restrict__ Hmat,
                                                  const float* __restrict__ dsort,
                                                  const int* __restrict__ dperm,
                                                  const float* __restrict__ tsort,
                                                  const int* __restrict__ tperm,
                                                  const float* __restrict__ chunkP, const float* __restrict__ chunkS,
                                                  const float* __restrict__ chunkPw, const float* __restrict__ chunkSw,
                                                  const float* __restrict__ bias,
                                                  float* __restrict__ out) {
  __shared__ float PPloc[CH + 1][64], PSloc[CH + 1][64];
  __shared__ float ppwLoc[CH + 1], pswLoc[CH + 1];
  __shared__ float subP[4][64], subS[4][64], sall[4][64];
  __shared__ float subPw[4], subSw[4];

  const int ch = blockIdx.x & (NCH - 1);
  const int g = blockIdx.x >> 7;
  const int b = g >> 2, h = g & 3;
  const int c = threadIdx.x & 63;
  const int w = threadIdx.x >> 6;
  const int gNN = g * NN;
  const size_t bNN = (size_t)b * NN;
  const int h64 = h * 64;
  const float dmax = dsort[gNN + NN - 1];
  const int kw0 = ch * CH + w * SUB;

  // --- phase 1: gather chunk H, weights, intra-sub inclusive prefixes ---
  int j8[SUB]; float d8[SUB], hv8[SUB];
  #pragma unroll
  for (int l = 0; l < SUB; ++l) j8[l] = dperm[gNN + kw0 + l];
  #pragma unroll
  for (int l = 0; l < SUB; ++l) d8[l] = dsort[gNN + kw0 + l];
  #pragma unroll
  for (int l = 0; l < SUB; ++l) hv8[l] = __half2float(Hmat[(bNN + j8[l]) * NF + h64 + c]);

  float ppv[SUB], psv[SUB], ppw[SUB], psw[SUB];
  {
    float ap = 0.f, as = 0.f, aw = 0.f, aswv = 0.f;
    #pragma unroll
    for (int l = 0; l < SUB; ++l) {
      float wp = __expf(0.2f * (d8[l] - dmax));
      float ws = __expf(d8[l] - dmax);
      ap += wp * hv8[l]; as += ws * hv8[l]; aw += wp; aswv += ws;
      ppv[l] = ap; psv[l] = as; ppw[l] = aw; psw[l] = aswv;
    }
    subP[w][c] = ap; subS[w][c] = as;
    if (c == 0) { subPw[w] = aw; subSw[w] = aswv; }
  }
  __syncthreads();

  // --- phase 2: add earlier-subchunk offsets, publish local prefix tables ---
  {
    float oP = 0.f, oS = 0.f, oPw = 0.f, oSw = 0.f;
    #pragma unroll
    for (int t = 0; t < 4; ++t) {
      if (t < w) { oP += subP[t][c]; oS += subS[t][c]; oPw += subPw[t]; oSw += subSw[t]; }
    }
    #pragma unroll
    for (int l = 0; l < SUB; ++l) {
      PPloc[w * SUB + 1 + l][c] = ppv[l] + oP;
      PSloc[w * SUB + 1 + l][c] = psv[l] + oS;
    }
    if (c == 0) {
      #pragma unroll
      for (int l = 0; l < SUB; ++l) {
        ppwLoc[w * SUB + 1 + l] = ppw[l] + oPw;
        pswLoc[w * SUB + 1 + l] = psw[l] + oSw;
      }
    }
    if (w == 0) {
      PPloc[0][c] = 0.f; PSloc[0][c] = 0.f;
      if (c == 0) { ppwLoc[0] = 0.f; pswLoc[0] = 0.f; }
    }
  }
  __syncthreads();

  // --- phase 3: cross-chunk channel offsets (prefix < ch) + total S, split over waves ---
  {
    float pp = 0.f, sp = 0.f, sa = 0.f;
    for (int t = w; t < ch; t += 4) pp += chunkP[(g * NCH + t) * 64 + c];
    for (int t = w; t < NCH; t += 4) {
      float v = chunkS[(g * NCH + t) * 64 + c];
      sa += v;
      if (t < ch) sp += v;
    }
    subP[w][c] = pp; subS[w][c] = sp; sall[w][c] = sa;
  }

  // scalar chunk offsets: lane-parallel + wave reduce (redundant per wave, cheap)
  float offPw, offSw, totSw;
  {
    float w1 = chunkPw[g * NCH + c];
    float w2 = chunkPw[g * NCH + 64 + c];
    float pwo = (c < ch ? w1 : 0.f) + (c + 64 < ch ? w2 : 0.f);
    float u1 = chunkSw[g * NCH + c];
    float u2 = chunkSw[g * NCH + 64 + c];
    float swo = (c < ch ? u1 : 0.f) + (c + 64 < ch ? u2 : 0.f);
    float stw = u1 + u2;
    #pragma unroll
    for (int off = 1; off < 64; off <<= 1) {
      pwo += __shfl_xor(pwo, off);
      swo += __shfl_xor(swo, off);
      stw += __shfl_xor(stw, off);
    }
    offPw = pwo; offSw = swo; totSw = stw;
  }
  __syncthreads();

  const float offP = subP[0][c] + subP[1][c] + subP[2][c] + subP[3][c];
  const float offS = subS[0][c] + subS[1][c] + subS[2][c] + subS[3][c];
  const float totS = sall[0][c] + sall[1][c] + sall[2][c] + sall[3][c];

  // --- phase 4: row range via binary search on t-sorted keys ---
  const float* ts = tsort + gNN;
  int rlo, rhi;
  {
    float blo = dsort[gNN + ch * CH];
    if (ch == 0) rlo = 0;
    else {
      int lo = 0, hi = NN;
      while (lo < hi) { int mid = (lo + hi) >> 1; if (ts[mid] < blo) lo = mid + 1; else hi = mid; }
      rlo = lo;
    }
    if (ch == NCH - 1) rhi = NN;
    else {
      float bhi = dsort[gNN + (ch + 1) * CH];
      int lo = 0, hi = NN;
      while (lo < hi) { int mid = (lo + hi) >> 1; if (ts[mid] < bhi) lo = mid + 1; else hi = mid; }
      rhi = lo;
    }
  }

  // lane c<32 holds chunk d value for rank-in-chunk ballot
  const float myd = (c < 32) ? dsort[gNN + ch * CH + c] : __int_as_float(0x7f800000);
  const float biasv = bias[h64 + c];

  // --- phase 5: serve rows ---
  for (int r = rlo + w; r < rhi; r += 4) {
    const float t = ts[r];
    const int i = tperm[gNN + r];
    const int mloc = __popcll(__ballot(myd <= t));
    const float numB = PPloc[mloc][c] + offP;
    const float denB = ppwLoc[mloc] + offPw;
    const float numA = totS - (PSloc[mloc][c] + offS);
    const float denA = totSw - (pswLoc[mloc] + offSw);
    const float si = -t;
    const float sdm = si + dmax;
    const float mx = sdm > 0.f ? sdm : 0.2f * sdm;
    const float alpha = __expf(sdm - mx);
    const float beta = __expf(0.2f * sdm - mx);
    const float den = alpha * denA + beta * denB;
    float val = (alpha * numA + beta * numB) / den + biasv;
    float o = val > 0.f ? val : expm1f(val);
    out[(bNN + i) * NF + h64 + c] = o;
  }
}

extern "C" void kernel_launch(void* const* d_in, const int* in_sizes, int n_in,
                              void* d_out, int out_size, void* d_ws, size_t ws_size,
                              hipStream_t stream) {
  const float* X = (const float*)d_in[0];       // [2,4096,128]
  const float* W = (const float*)d_in[1];       // [128,256]
  const float* a_src = (const float*)d_in[2];   // [4,64,1]
  const float* a_dst = (const float*)d_in[3];   // [4,64,1]
  const float* bias = (const float*)d_in[4];    // [256]
  float* out = (float*)d_out;                   // [2,4096,256]

  float* ws = (float*)d_ws;
  float* s_arr = ws;                        // 8*4096
  float* d_arr = s_arr + NG * NN;           // 8*4096
  float* dsort = d_arr + NG * NN;           // 8*4096
  int* dperm = (int*)(dsort + NG * NN);     // 8*4096
  float* tsort = (float*)(dperm + NG * NN); // 8*4096
  int* tperm = (int*)(tsort + NG * NN);     // 8*4096
  float* chunkP = (float*)(tperm + NG * NN);    // 8*128*64
  float* chunkS = chunkP + NG * NCH * 64;
  float* chunkPw = chunkS + NG * NCH * 64;      // 8*128
  float* chunkSw = chunkPw + NG * NCH;
  __half* Hmat = (__half*)(chunkSw + NG * NCH); // 2*4096*256 halves (4 MB)

  k_gemm<<<dim3(128, 4), 256, 0, stream>>>(X, W, a_src, a_dst, Hmat, s_arr, d_arr);
  k_sort<<<2 * NG, 1024, 0, stream>>>(d_arr, s_arr, dsort, dperm, tsort, tperm);
  k_part<<<dim3(NCH, NG), 256, 0, stream>>>(Hmat, dsort, dperm, chunkP, chunkS, chunkPw, chunkSw);
  k_serve<<<NG * NCH, 256, 0, stream>>>(Hmat, dsort, dperm, tsort, tperm,
                                        chunkP, chunkS, chunkPw, chunkSw, bias, out);
}

// Round 9
// 61.560 us; speedup vs baseline: 5.8207x; 1.1292x over previous
//
#include <hip/hip_runtime.h>
#include <hip/hip_fp16.h>
#include <math.h>

#define NH 4        // heads
#define DD 64       // out features per head
#define NF 256      // NH*DD
#define KF 128      // in features
#define NN 4096     // nodes
#define NB 2        // batch
#define NG 8        // NB*NH groups
#define CH 32       // scan chunk length
#define NCH 128     // NN / CH
#define SUB 8       // elements per wave within a chunk (4 waves * 8 = CH)

typedef _Float16 h8_t __attribute__((ext_vector_type(8)));
typedef float f4_t __attribute__((ext_vector_type(4)));

// ---------------- Kernel 1: H = X @ W via fp16 MFMA (fp32 accum), fused s/d epilogue ----------------
__global__ __launch_bounds__(256) void k_gemm(const float* __restrict__ X,
                                              const float* __restrict__ W,
                                              const float* __restrict__ a_src,
                                              const float* __restrict__ a_dst,
                                              __half* __restrict__ Hout,
                                              float* __restrict__ s_arr,
                                              float* __restrict__ d_arr) {
  __shared__ float As[64][132];        // X tile, fp32
  __shared__ _Float16 WT[64][136];     // W block transposed [col][k] fp16
  const int bm = blockIdx.x;           // 0..127 row tile
  const int bn = blockIdx.y;           // 0..3 head
  const int tid = threadIdx.x;

  for (int i = tid; i < 64 * 32; i += 256) {
    int r = i >> 5, c4 = i & 31;
    float4 v = *(const float4*)(X + ((size_t)(bm * 64 + r)) * KF + c4 * 4);
    *(float4*)&As[r][c4 * 4] = v;
  }
  for (int i = tid; i < 64 * 128; i += 256) {
    int k = i >> 6, c = i & 63;
    WT[c][k] = (_Float16)W[(size_t)k * NF + bn * 64 + c];
  }
  __syncthreads();

  const int lane = tid & 63, w = tid >> 6;
  const int l15 = lane & 15, lq = lane >> 4;

  f4_t acc[4] = {f4_t{0.f,0.f,0.f,0.f}, f4_t{0.f,0.f,0.f,0.f},
                 f4_t{0.f,0.f,0.f,0.f}, f4_t{0.f,0.f,0.f,0.f}};

  #pragma unroll
  for (int kk = 0; kk < 4; ++kk) {
    const int koff = kk * 32 + lq * 8;
    h8_t a;
    {
      const float* ap = &As[w * 16 + l15][koff];
      float4 x0 = *(const float4*)ap;
      float4 x1 = *(const float4*)(ap + 4);
      a[0] = (_Float16)x0.x; a[1] = (_Float16)x0.y;
      a[2] = (_Float16)x0.z; a[3] = (_Float16)x0.w;
      a[4] = (_Float16)x1.x; a[5] = (_Float16)x1.y;
      a[6] = (_Float16)x1.z; a[7] = (_Float16)x1.w;
    }
    #pragma unroll
    for (int t = 0; t < 4; ++t) {
      h8_t b = *(const h8_t*)&WT[t * 16 + l15][koff];
      acc[t] = __builtin_amdgcn_mfma_f32_16x16x32_f16(a, b, acc[t], 0, 0, 0);
    }
  }

  float asv[4], adv[4];
  #pragma unroll
  for (int t = 0; t < 4; ++t) {
    asv[t] = a_src[bn * 64 + t * 16 + l15];
    adv[t] = a_dst[bn * 64 + t * 16 + l15];
  }
  #pragma unroll
  for (int j = 0; j < 4; ++j) {
    const int grow = bm * 64 + w * 16 + lq * 4 + j;
    float ps = 0.f, pd = 0.f;
    #pragma unroll
    for (int t = 0; t < 4; ++t) {
      float hv = acc[t][j];
      Hout[(size_t)grow * NF + bn * 64 + t * 16 + l15] = __float2half(hv);
      ps += hv * asv[t];
      pd += hv * adv[t];
    }
    #pragma unroll
    for (int off = 1; off < 16; off <<= 1) {
      ps += __shfl_xor(ps, off);
      pd += __shfl_xor(pd, off);
    }
    if (l15 == 0) {
      int b = grow >> 12, n = grow & (NN - 1);
      int g = b * NH + bn;
      s_arr[g * NN + n] = ps;
      d_arr[g * NN + n] = pd;
    }
  }
}

// ---------------- Kernel 2: packed-key bitonic sort (20-bit rounded key | 12-bit index) ----------------
// blocks 0..7: d ascending -> (dsort, dperm). blocks 8..15: t = -s ascending -> (tsort, tperm).
// Exact values re-gathered from LDS at the end; near-tie inversions are benign (LeakyReLU kink continuity).
__global__ __launch_bounds__(1024) void k_sort(const float* __restrict__ d_arr,
                                               const float* __restrict__ s_arr,
                                               float* __restrict__ dsort, int* __restrict__ dperm,
                                               float* __restrict__ tsort, int* __restrict__ tperm) {
  __shared__ uint4 skey[1024];     // 16 KB
  __shared__ float vals[NN];       // 16 KB exact values for final gather
  const int bid = blockIdx.x;
  const bool isT = bid >= NG;
  const int g = isT ? bid - NG : bid;
  const float* src = isT ? s_arr : d_arr;
  float* okey = isT ? tsort : dsort;
  int* operm = isT ? tperm : dperm;
  const int tid = threadIdx.x;

  unsigned kk[4];
  {
    float4 v = *(const float4*)(src + g * NN + 4 * tid);
    float f[4] = {v.x, v.y, v.z, v.w};
    #pragma unroll
    for (int r = 0; r < 4; ++r) {
      float fv = isT ? -f[r] : f[r];
      vals[4 * tid + r] = fv;
      unsigned u = __float_as_uint(fv);
      u = (u & 0x80000000u) ? ~u : (u | 0x80000000u);   // order-preserving transform
      kk[r] = (u & 0xFFFFF000u) | (unsigned)(4 * tid + r);
    }
  }

  #define CEU(a, b, asc)                                           \
    do { unsigned ka = kk[a], kb = kk[b];                          \
      unsigned mn = ka < kb ? ka : kb, mx = ka < kb ? kb : ka;     \
      kk[a] = (asc) ? mn : mx; kk[b] = (asc) ? mx : mn; } while (0)

  CEU(0, 1, true);
  CEU(2, 3, false);

  #pragma unroll
  for (int k = 4; k <= NN; k <<= 1) {
    const bool asc = (tid & (k >> 2)) == 0;
    #pragma unroll
    for (int j = k >> 1; j > 0; j >>= 1) {
      if (j >= 256) {
        const int tdist = j >> 2;
        skey[tid] = make_uint4(kk[0], kk[1], kk[2], kk[3]);
        __syncthreads();
        uint4 p = skey[tid ^ tdist];
        const bool lower = (tid & tdist) == 0;
        const bool keepMin = (lower == asc);
        #pragma unroll
        for (int r = 0; r < 4; ++r) {
          unsigned pk = (&p.x)[r];
          unsigned mn = kk[r] < pk ? kk[r] : pk;
          unsigned mx = kk[r] < pk ? pk : kk[r];
          kk[r] = keepMin ? mn : mx;
        }
        __syncthreads();
      } else if (j >= 4) {
        const int dist = j >> 2;
        const bool lower = (tid & dist) == 0;
        const bool keepMin = (lower == asc);
        #pragma unroll
        for (int r = 0; r < 4; ++r) {
          unsigned pk = (unsigned)__shfl_xor((int)kk[r], dist);
          unsigned mn = kk[r] < pk ? kk[r] : pk;
          unsigned mx = kk[r] < pk ? pk : kk[r];
          kk[r] = keepMin ? mn : mx;
        }
      } else if (j == 2) {
        CEU(0, 2, asc);
        CEU(1, 3, asc);
      } else {
        CEU(0, 1, asc);
        CEU(2, 3, asc);
      }
    }
  }
  #undef CEU

  __syncthreads();
  float4 ov;
  int4 op;
  #pragma unroll
  for (int r = 0; r < 4; ++r) {
    int idx = (int)(kk[r] & 0xFFFu);
    (&ov.x)[r] = vals[idx];
    (&op.x)[r] = idx;
  }
  *(float4*)(okey + g * NN + 4 * tid) = ov;
  *(int4*)(operm + g * NN + 4 * tid) = op;
}

// ---------------- Kernel 3: per-chunk partial sums ----------------
__global__ __launch_bounds__(256) void k_part(const __half* __restrict__ Hmat,
                                              const float* __restrict__ dsort,
                                              const int* __restrict__ dperm,
                                              float* __restrict__ chunkP, float* __restrict__ chunkS,
                                              float* __restrict__ chunkPw, float* __restrict__ chunkSw) {
  __shared__ float subP[4][64], subS[4][64];
  __shared__ float subPw[4], subSw[4];
  const int ch = blockIdx.x;   // 0..127
  const int g = blockIdx.y;    // 0..7
  const int b = g >> 2, h = g & 3;
  const int c = threadIdx.x & 63;
  const int w = threadIdx.x >> 6;
  const int gNN = g * NN;
  const size_t bNN = (size_t)b * NN;
  const int h64 = h * 64;
  const float dmax = dsort[gNN + NN - 1];
  const int kw0 = ch * CH + w * SUB;

  int j8[SUB]; float d8[SUB], hv8[SUB];
  #pragma unroll
  for (int l = 0; l < SUB; ++l) j8[l] = dperm[gNN + kw0 + l];
  #pragma unroll
  for (int l = 0; l < SUB; ++l) d8[l] = dsort[gNN + kw0 + l];
  #pragma unroll
  for (int l = 0; l < SUB; ++l) hv8[l] = __half2float(Hmat[(bNN + j8[l]) * NF + h64 + c]);

  float pa = 0.f, sa = 0.f, pw = 0.f, sw = 0.f;
  #pragma unroll
  for (int l = 0; l < SUB; ++l) {
    float wp = __expf(0.2f * (d8[l] - dmax));
    float ws = __expf(d8[l] - dmax);
    pa += wp * hv8[l]; sa += ws * hv8[l]; pw += wp; sw += ws;
  }
  subP[w][c] = pa; subS[w][c] = sa;
  if (c == 0) { subPw[w] = pw; subSw[w] = sw; }
  __syncthreads();

  if (w == 0) {
    float tp = subP[0][c] + subP[1][c] + subP[2][c] + subP[3][c];
    float ts = subS[0][c] + subS[1][c] + subS[2][c] + subS[3][c];
    chunkP[(g * NCH + ch) * 64 + c] = tp;
    chunkS[(g * NCH + ch) * 64 + c] = ts;
    if (c == 0) {
      chunkPw[g * NCH + ch] = subPw[0] + subPw[1] + subPw[2] + subPw[3];
      chunkSw[g * NCH + ch] = subSw[0] + subSw[1] + subSw[2] + subSw[3];
    }
  }
}

// ---------------- Kernel 4: serve rows from local chunk prefixes ----------------
__global__ __launch_bounds__(256, 4) void k_serve(const __half* __restrict__ Hmat,
                                                  const float* __restrict__ dsort,
                                                  const int* __restrict__ dperm,
                                                  const float* __restrict__ tsort,
                                                  const int* __restrict__ tperm,
                                                  const float* __restrict__ chunkP, const float* __restrict__ chunkS,
                                                  const float* __restrict__ chunkPw, const float* __restrict__ chunkSw,
                                                  const float* __restrict__ bias,
                                                  float* __restrict__ out) {
  __shared__ float PPloc[CH + 1][64], PSloc[CH + 1][64];
  __shared__ float ppwLoc[CH + 1], pswLoc[CH + 1];
  __shared__ float subP[4][64], subS[4][64], sall[4][64];
  __shared__ float subPw[4], subSw[4];

  const int ch = blockIdx.x & (NCH - 1);
  const int g = blockIdx.x >> 7;
  const int b = g >> 2, h = g & 3;
  const int c = threadIdx.x & 63;
  const int w = threadIdx.x >> 6;
  const int gNN = g * NN;
  const size_t bNN = (size_t)b * NN;
  const int h64 = h * 64;
  const float dmax = dsort[gNN + NN - 1];
  const int kw0 = ch * CH + w * SUB;

  // --- phase 1: gather chunk H, weights, intra-sub inclusive prefixes ---
  int j8[SUB]; float d8[SUB], hv8[SUB];
  #pragma unroll
  for (int l = 0; l < SUB; ++l) j8[l] = dperm[gNN + kw0 + l];
  #pragma unroll
  for (int l = 0; l < SUB; ++l) d8[l] = dsort[gNN + kw0 + l];
  #pragma unroll
  for (int l = 0; l < SUB; ++l) hv8[l] = __half2float(Hmat[(bNN + j8[l]) * NF + h64 + c]);

  float ppv[SUB], psv[SUB], ppw[SUB], psw[SUB];
  {
    float ap = 0.f, as = 0.f, aw = 0.f, aswv = 0.f;
    #pragma unroll
    for (int l = 0; l < SUB; ++l) {
      float wp = __expf(0.2f * (d8[l] - dmax));
      float ws = __expf(d8[l] - dmax);
      ap += wp * hv8[l]; as += ws * hv8[l]; aw += wp; aswv += ws;
      ppv[l] = ap; psv[l] = as; ppw[l] = aw; psw[l] = aswv;
    }
    subP[w][c] = ap; subS[w][c] = as;
    if (c == 0) { subPw[w] = aw; subSw[w] = aswv; }
  }
  __syncthreads();

  // --- phase 2: add earlier-subchunk offsets, publish local prefix tables ---
  {
    float oP = 0.f, oS = 0.f, oPw = 0.f, oSw = 0.f;
    #pragma unroll
    for (int t = 0; t < 4; ++t) {
      if (t < w) { oP += subP[t][c]; oS += subS[t][c]; oPw += subPw[t]; oSw += subSw[t]; }
    }
    #pragma unroll
    for (int l = 0; l < SUB; ++l) {
      PPloc[w * SUB + 1 + l][c] = ppv[l] + oP;
      PSloc[w * SUB + 1 + l][c] = psv[l] + oS;
    }
    if (c == 0) {
      #pragma unroll
      for (int l = 0; l < SUB; ++l) {
        ppwLoc[w * SUB + 1 + l] = ppw[l] + oPw;
        pswLoc[w * SUB + 1 + l] = psw[l] + oSw;
      }
    }
    if (w == 0) {
      PPloc[0][c] = 0.f; PSloc[0][c] = 0.f;
      if (c == 0) { ppwLoc[0] = 0.f; pswLoc[0] = 0.f; }
    }
  }
  __syncthreads();

  // --- phase 3: cross-chunk channel offsets (prefix < ch) + total S, split over waves ---
  {
    float pp = 0.f, sp = 0.f, sa = 0.f;
    for (int t = w; t < ch; t += 4) pp += chunkP[(g * NCH + t) * 64 + c];
    for (int t = w; t < NCH; t += 4) {
      float v = chunkS[(g * NCH + t) * 64 + c];
      sa += v;
      if (t < ch) sp += v;
    }
    subP[w][c] = pp; subS[w][c] = sp; sall[w][c] = sa;
  }

  float offPw, offSw, totSw;
  {
    float w1 = chunkPw[g * NCH + c];
    float w2 = chunkPw[g * NCH + 64 + c];
    float pwo = (c < ch ? w1 : 0.f) + (c + 64 < ch ? w2 : 0.f);
    float u1 = chunkSw[g * NCH + c];
    float u2 = chunkSw[g * NCH + 64 + c];
    float swo = (c < ch ? u1 : 0.f) + (c + 64 < ch ? u2 : 0.f);
    float stw = u1 + u2;
    #pragma unroll
    for (int off = 1; off < 64; off <<= 1) {
      pwo += __shfl_xor(pwo, off);
      swo += __shfl_xor(swo, off);
      stw += __shfl_xor(stw, off);
    }
    offPw = pwo; offSw = swo; totSw = stw;
  }
  __syncthreads();

  const float offP = subP[0][c] + subP[1][c] + subP[2][c] + subP[3][c];
  const float offS = subS[0][c] + subS[1][c] + subS[2][c] + subS[3][c];
  const float totS = sall[0][c] + sall[1][c] + sall[2][c] + sall[3][c];

  // --- phase 4: row range via binary search on t-sorted keys ---
  const float* ts = tsort + gNN;
  int rlo, rhi;
  {
    float blo = dsort[gNN + ch * CH];
    if (ch == 0) rlo = 0;
    else {
      int lo = 0, hi = NN;
      while (lo < hi) { int mid = (lo + hi) >> 1; if (ts[mid] < blo) lo = mid + 1; else hi = mid; }
      rlo = lo;
    }
    if (ch == NCH - 1) rhi = NN;
    else {
      float bhi = dsort[gNN + (ch + 1) * CH];
      int lo = 0, hi = NN;
      while (lo < hi) { int mid = (lo + hi) >> 1; if (ts[mid] < bhi) lo = mid + 1; else hi = mid; }
      rhi = lo;
    }
  }

  const float myd = (c < 32) ? dsort[gNN + ch * CH + c] : __int_as_float(0x7f800000);
  const float biasv = bias[h64 + c];

  // --- phase 5: serve rows ---
  for (int r = rlo + w; r < rhi; r += 4) {
    const float t = ts[r];
    const int i = tperm[gNN + r];
    const int mloc = __popcll(__ballot(myd <= t));
    const float numB = PPloc[mloc][c] + offP;
    const float denB = ppwLoc[mloc] + offPw;
    const float numA = totS - (PSloc[mloc][c] + offS);
    const float denA = totSw - (pswLoc[mloc] + offSw);
    const float si = -t;
    const float sdm = si + dmax;
    const float mx = sdm > 0.f ? sdm : 0.2f * sdm;
    const float alpha = __expf(sdm - mx);
    const float beta = __expf(0.2f * sdm - mx);
    const float den = alpha * denA + beta * denB;
    float val = (alpha * numA + beta * numB) / den + biasv;
    float o = val > 0.f ? val : expm1f(val);
    out[(bNN + i) * NF + h64 + c] = o;
  }
}

extern "C" void kernel_launch(void* const* d_in, const int* in_sizes, int n_in,
                              void* d_out, int out_size, void* d_ws, size_t ws_size,
                              hipStream_t stream) {
  const float* X = (const float*)d_in[0];       // [2,4096,128]
  const float* W = (const float*)d_in[1];       // [128,256]
  const float* a_src = (const float*)d_in[2];   // [4,64,1]
  const float* a_dst = (const float*)d_in[3];   // [4,64,1]
  const float* bias = (const float*)d_in[4];    // [256]
  float* out = (float*)d_out;                   // [2,4096,256]

  float* ws = (float*)d_ws;
  float* s_arr = ws;                        // 8*4096
  float* d_arr = s_arr + NG * NN;           // 8*4096
  float* dsort = d_arr + NG * NN;           // 8*4096
  int* dperm = (int*)(dsort + NG * NN);     // 8*4096
  float* tsort = (float*)(dperm + NG * NN); // 8*4096
  int* tperm = (int*)(tsort + NG * NN);     // 8*4096
  float* chunkP = (float*)(tperm + NG * NN);    // 8*128*64
  float* chunkS = chunkP + NG * NCH * 64;
  float* chunkPw = chunkS + NG * NCH * 64;      // 8*128
  float* chunkSw = chunkPw + NG * NCH;
  __half* Hmat = (__half*)(chunkSw + NG * NCH); // 2*4096*256 halves (4 MB)

  k_gemm<<<dim3(128, 4), 256, 0, stream>>>(X, W, a_src, a_dst, Hmat, s_arr, d_arr);
  k_sort<<<2 * NG, 1024, 0, stream>>>(d_arr, s_arr, dsort, dperm, tsort, tperm);
  k_part<<<dim3(NCH, NG), 256, 0, stream>>>(Hmat, dsort, dperm, chunkP, chunkS, chunkPw, chunkSw);
  k_serve<<<NG * NCH, 256, 0, stream>>>(Hmat, dsort, dperm, tsort, tperm,
                                        chunkP, chunkS, chunkPw, chunkSw, bias, out);
}

// Round 10
// 57.682 us; speedup vs baseline: 6.2120x; 1.0672x over previous
//
#include <hip/hip_runtime.h>
#include <hip/hip_fp16.h>
#include <math.h>

#define NH 4        // heads
#define DD 64       // out features per head
#define NF 256      // NH*DD
#define KF 128      // in features
#define NN 4096     // nodes
#define NB 2        // batch
#define NG 8        // NB*NH groups
#define CH 32       // scan chunk length
#define NCH 128     // NN / CH
#define SUB 8       // elements per wave within a chunk (4 waves * 8 = CH)

typedef _Float16 h8_t __attribute__((ext_vector_type(8)));
typedef float f4_t __attribute__((ext_vector_type(4)));

// ---------------- Kernel 1: H = X @ W via fp16 MFMA (fp32 accum), fused s/d epilogue ----------------
__global__ __launch_bounds__(256) void k_gemm(const float* __restrict__ X,
                                              const float* __restrict__ W,
                                              const float* __restrict__ a_src,
                                              const float* __restrict__ a_dst,
                                              __half* __restrict__ Hout,
                                              float* __restrict__ s_arr,
                                              float* __restrict__ d_arr) {
  __shared__ float As[64][132];        // X tile, fp32
  __shared__ _Float16 WT[64][136];     // W block transposed [col][k] fp16
  const int bm = blockIdx.x;           // 0..127 row tile
  const int bn = blockIdx.y;           // 0..3 head
  const int tid = threadIdx.x;

  for (int i = tid; i < 64 * 32; i += 256) {
    int r = i >> 5, c4 = i & 31;
    float4 v = *(const float4*)(X + ((size_t)(bm * 64 + r)) * KF + c4 * 4);
    *(float4*)&As[r][c4 * 4] = v;
  }
  for (int i = tid; i < 64 * 128; i += 256) {
    int k = i >> 6, c = i & 63;
    WT[c][k] = (_Float16)W[(size_t)k * NF + bn * 64 + c];
  }
  __syncthreads();

  const int lane = tid & 63, w = tid >> 6;
  const int l15 = lane & 15, lq = lane >> 4;

  f4_t acc[4] = {f4_t{0.f,0.f,0.f,0.f}, f4_t{0.f,0.f,0.f,0.f},
                 f4_t{0.f,0.f,0.f,0.f}, f4_t{0.f,0.f,0.f,0.f}};

  #pragma unroll
  for (int kk = 0; kk < 4; ++kk) {
    const int koff = kk * 32 + lq * 8;
    h8_t a;
    {
      const float* ap = &As[w * 16 + l15][koff];
      float4 x0 = *(const float4*)ap;
      float4 x1 = *(const float4*)(ap + 4);
      a[0] = (_Float16)x0.x; a[1] = (_Float16)x0.y;
      a[2] = (_Float16)x0.z; a[3] = (_Float16)x0.w;
      a[4] = (_Float16)x1.x; a[5] = (_Float16)x1.y;
      a[6] = (_Float16)x1.z; a[7] = (_Float16)x1.w;
    }
    #pragma unroll
    for (int t = 0; t < 4; ++t) {
      h8_t b = *(const h8_t*)&WT[t * 16 + l15][koff];
      acc[t] = __builtin_amdgcn_mfma_f32_16x16x32_f16(a, b, acc[t], 0, 0, 0);
    }
  }

  float asv[4], adv[4];
  #pragma unroll
  for (int t = 0; t < 4; ++t) {
    asv[t] = a_src[bn * 64 + t * 16 + l15];
    adv[t] = a_dst[bn * 64 + t * 16 + l15];
  }
  #pragma unroll
  for (int j = 0; j < 4; ++j) {
    const int grow = bm * 64 + w * 16 + lq * 4 + j;
    float ps = 0.f, pd = 0.f;
    #pragma unroll
    for (int t = 0; t < 4; ++t) {
      float hv = acc[t][j];
      Hout[(size_t)grow * NF + bn * 64 + t * 16 + l15] = __float2half(hv);
      ps += hv * asv[t];
      pd += hv * adv[t];
    }
    #pragma unroll
    for (int off = 1; off < 16; off <<= 1) {
      ps += __shfl_xor(ps, off);
      pd += __shfl_xor(pd, off);
    }
    if (l15 == 0) {
      int b = grow >> 12, n = grow & (NN - 1);
      int g = b * NH + bn;
      s_arr[g * NN + n] = ps;
      d_arr[g * NN + n] = pd;
    }
  }
}

// ---------------- Kernel 2: packed-key bitonic sort, 8-element ownership ----------------
// 512 threads; shuffles cover j=8..256, only 6 LDS passes (j>=512), conflict-free skey[r][512] layout.
__global__ __launch_bounds__(512) void k_sort(const float* __restrict__ d_arr,
                                              const float* __restrict__ s_arr,
                                              float* __restrict__ dsort, int* __restrict__ dperm,
                                              float* __restrict__ tsort, int* __restrict__ tperm) {
  __shared__ unsigned skey[8][512];    // 16 KB, stride-4B per r: conflict-free
  __shared__ float vals[NN];           // 16 KB exact values for final gather
  const int bid = blockIdx.x;
  const bool isT = bid >= NG;
  const int g = isT ? bid - NG : bid;
  const float* src = isT ? s_arr : d_arr;
  float* okey = isT ? tsort : dsort;
  int* operm = isT ? tperm : dperm;
  const int tid = threadIdx.x;         // 0..511

  unsigned kk[8];
  {
    float4 v0 = *(const float4*)(src + g * NN + 8 * tid);
    float4 v1 = *(const float4*)(src + g * NN + 8 * tid + 4);
    float f[8] = {v0.x, v0.y, v0.z, v0.w, v1.x, v1.y, v1.z, v1.w};
    #pragma unroll
    for (int r = 0; r < 8; ++r) {
      float fv = isT ? -f[r] : f[r];
      vals[8 * tid + r] = fv;
      unsigned u = __float_as_uint(fv);
      u = (u & 0x80000000u) ? ~u : (u | 0x80000000u);   // order-preserving transform
      kk[r] = (u & 0xFFFFF000u) | (unsigned)(8 * tid + r);
    }
  }

  #define CEU(a, b, asc)                                           \
    do { unsigned ka = kk[a], kb = kk[b];                          \
      unsigned mn = ka < kb ? ka : kb, mx = ka < kb ? kb : ka;     \
      kk[a] = (asc) ? mn : mx; kk[b] = (asc) ? mx : mn; } while (0)

  // k=2: asc per element = ((r&2)==0)
  CEU(0, 1, true); CEU(2, 3, false); CEU(4, 5, true); CEU(6, 7, false);
  // k=4: asc = ((r&4)==0); j=2 then j=1
  CEU(0, 2, true); CEU(1, 3, true); CEU(4, 6, false); CEU(5, 7, false);
  CEU(0, 1, true); CEU(2, 3, true); CEU(4, 5, false); CEU(6, 7, false);

  #pragma unroll
  for (int k = 8; k <= NN; k <<= 1) {
    const bool asc = (tid & (k >> 3)) == 0;
    #pragma unroll
    for (int j = k >> 1; j > 0; j >>= 1) {
      if (j >= 512) {
        const int tdist = j >> 3;              // 64, 128, 256
        #pragma unroll
        for (int r = 0; r < 8; ++r) skey[r][tid] = kk[r];
        __syncthreads();
        const bool keepMin = ((tid & tdist) == 0) == asc;
        #pragma unroll
        for (int r = 0; r < 8; ++r) {
          unsigned pk = skey[r][tid ^ tdist];
          unsigned mn = kk[r] < pk ? kk[r] : pk;
          unsigned mx = kk[r] < pk ? pk : kk[r];
          kk[r] = keepMin ? mn : mx;
        }
        __syncthreads();
      } else if (j >= 8) {
        const int dist = j >> 3;               // 1..32, within-wave
        const bool keepMin = ((tid & dist) == 0) == asc;
        #pragma unroll
        for (int r = 0; r < 8; ++r) {
          unsigned pk = (unsigned)__shfl_xor((int)kk[r], dist);
          unsigned mn = kk[r] < pk ? kk[r] : pk;
          unsigned mx = kk[r] < pk ? pk : kk[r];
          kk[r] = keepMin ? mn : mx;
        }
      } else if (j == 4) {
        CEU(0, 4, asc); CEU(1, 5, asc); CEU(2, 6, asc); CEU(3, 7, asc);
      } else if (j == 2) {
        CEU(0, 2, asc); CEU(1, 3, asc); CEU(4, 6, asc); CEU(5, 7, asc);
      } else {
        CEU(0, 1, asc); CEU(2, 3, asc); CEU(4, 5, asc); CEU(6, 7, asc);
      }
    }
  }
  #undef CEU

  // vals[] writes happened before the LDS-pass barriers -> visible
  float ov[8]; int op[8];
  #pragma unroll
  for (int r = 0; r < 8; ++r) {
    int idx = (int)(kk[r] & 0xFFFu);
    ov[r] = vals[idx];
    op[r] = idx;
  }
  *(float4*)(okey + g * NN + 8 * tid)     = make_float4(ov[0], ov[1], ov[2], ov[3]);
  *(float4*)(okey + g * NN + 8 * tid + 4) = make_float4(ov[4], ov[5], ov[6], ov[7]);
  *(int4*)(operm + g * NN + 8 * tid)      = make_int4(op[0], op[1], op[2], op[3]);
  *(int4*)(operm + g * NN + 8 * tid + 4)  = make_int4(op[4], op[5], op[6], op[7]);
}

// ---------------- Kernel 3: per-chunk partial sums ----------------
__global__ __launch_bounds__(256) void k_part(const __half* __restrict__ Hmat,
                                              const float* __restrict__ dsort,
                                              const int* __restrict__ dperm,
                                              float* __restrict__ chunkP, float* __restrict__ chunkS,
                                              float* __restrict__ chunkPw, float* __restrict__ chunkSw) {
  __shared__ float subP[4][64], subS[4][64];
  __shared__ float subPw[4], subSw[4];
  const int ch = blockIdx.x;   // 0..127
  const int g = blockIdx.y;    // 0..7
  const int b = g >> 2, h = g & 3;
  const int c = threadIdx.x & 63;
  const int w = threadIdx.x >> 6;
  const int gNN = g * NN;
  const size_t bNN = (size_t)b * NN;
  const int h64 = h * 64;
  const float dmax = dsort[gNN + NN - 1];
  const int kw0 = ch * CH + w * SUB;

  int j8[SUB]; float d8[SUB], hv8[SUB];
  #pragma unroll
  for (int l = 0; l < SUB; ++l) j8[l] = dperm[gNN + kw0 + l];
  #pragma unroll
  for (int l = 0; l < SUB; ++l) d8[l] = dsort[gNN + kw0 + l];
  #pragma unroll
  for (int l = 0; l < SUB; ++l) hv8[l] = __half2float(Hmat[(bNN + j8[l]) * NF + h64 + c]);

  float pa = 0.f, sa = 0.f, pw = 0.f, sw = 0.f;
  #pragma unroll
  for (int l = 0; l < SUB; ++l) {
    float wp = __expf(0.2f * (d8[l] - dmax));
    float w2 = wp * wp;
    float ws = w2 * w2 * wp;                  // exp(d-dmax) = wp^5
    pa += wp * hv8[l]; sa += ws * hv8[l]; pw += wp; sw += ws;
  }
  subP[w][c] = pa; subS[w][c] = sa;
  if (c == 0) { subPw[w] = pw; subSw[w] = sw; }
  __syncthreads();

  if (w == 0) {
    float tp = subP[0][c] + subP[1][c] + subP[2][c] + subP[3][c];
    float ts = subS[0][c] + subS[1][c] + subS[2][c] + subS[3][c];
    chunkP[(g * NCH + ch) * 64 + c] = tp;
    chunkS[(g * NCH + ch) * 64 + c] = ts;
    if (c == 0) {
      chunkPw[g * NCH + ch] = subPw[0] + subPw[1] + subPw[2] + subPw[3];
      chunkSw[g * NCH + ch] = subSw[0] + subSw[1] + subSw[2] + subSw[3];
    }
  }
}

// ---------------- Kernel 4: serve rows from local chunk prefixes ----------------
__global__ __launch_bounds__(256, 4) void k_serve(const __half* __restrict__ Hmat,
                                                  const float* __restrict__ dsort,
                                                  const int* __restrict__ dperm,
                                                  const float* __restrict__ tsort,
                                                  const int* __restrict__ tperm,
                                                  const float* __restrict__ chunkP, const float* __restrict__ chunkS,
                                                  const float* __restrict__ chunkPw, const float* __restrict__ chunkSw,
                                                  const float* __restrict__ bias,
                                                  float* __restrict__ out) {
  __shared__ float PPloc[CH + 1][64], PSloc[CH + 1][64];
  __shared__ float ppwLoc[CH + 1], pswLoc[CH + 1];
  __shared__ float subP[4][64], subS[4][64], sall[4][64];
  __shared__ float subPw[4], subSw[4];

  const int ch = blockIdx.x & (NCH - 1);
  const int g = blockIdx.x >> 7;
  const int b = g >> 2, h = g & 3;
  const int c = threadIdx.x & 63;
  const int w = threadIdx.x >> 6;
  const int gNN = g * NN;
  const size_t bNN = (size_t)b * NN;
  const int h64 = h * 64;
  const float dmax = dsort[gNN + NN - 1];
  const int kw0 = ch * CH + w * SUB;

  // --- phase 1: gather chunk H, weights, intra-sub inclusive prefixes ---
  int j8[SUB]; float d8[SUB], hv8[SUB];
  #pragma unroll
  for (int l = 0; l < SUB; ++l) j8[l] = dperm[gNN + kw0 + l];
  #pragma unroll
  for (int l = 0; l < SUB; ++l) d8[l] = dsort[gNN + kw0 + l];
  #pragma unroll
  for (int l = 0; l < SUB; ++l) hv8[l] = __half2float(Hmat[(bNN + j8[l]) * NF + h64 + c]);

  float ppv[SUB], psv[SUB], ppw[SUB], psw[SUB];
  {
    float ap = 0.f, as = 0.f, aw = 0.f, aswv = 0.f;
    #pragma unroll
    for (int l = 0; l < SUB; ++l) {
      float wp = __expf(0.2f * (d8[l] - dmax));
      float w2 = wp * wp;
      float ws = w2 * w2 * wp;                // exp(d-dmax) = wp^5
      ap += wp * hv8[l]; as += ws * hv8[l]; aw += wp; aswv += ws;
      ppv[l] = ap; psv[l] = as; ppw[l] = aw; psw[l] = aswv;
    }
    subP[w][c] = ap; subS[w][c] = as;
    if (c == 0) { subPw[w] = aw; subSw[w] = aswv; }
  }
  __syncthreads();

  // --- phase 2: add earlier-subchunk offsets, publish local prefix tables ---
  {
    float oP = 0.f, oS = 0.f, oPw = 0.f, oSw = 0.f;
    #pragma unroll
    for (int t = 0; t < 4; ++t) {
      if (t < w) { oP += subP[t][c]; oS += subS[t][c]; oPw += subPw[t]; oSw += subSw[t]; }
    }
    #pragma unroll
    for (int l = 0; l < SUB; ++l) {
      PPloc[w * SUB + 1 + l][c] = ppv[l] + oP;
      PSloc[w * SUB + 1 + l][c] = psv[l] + oS;
    }
    if (c == 0) {
      #pragma unroll
      for (int l = 0; l < SUB; ++l) {
        ppwLoc[w * SUB + 1 + l] = ppw[l] + oPw;
        pswLoc[w * SUB + 1 + l] = psw[l] + oSw;
      }
    }
    if (w == 0) {
      PPloc[0][c] = 0.f; PSloc[0][c] = 0.f;
      if (c == 0) { ppwLoc[0] = 0.f; pswLoc[0] = 0.f; }
    }
  }
  __syncthreads();

  // --- phase 3: cross-chunk channel offsets (prefix < ch) + total S, split over waves ---
  {
    float pp = 0.f, sp = 0.f, sa = 0.f;
    for (int t = w; t < ch; t += 4) pp += chunkP[(g * NCH + t) * 64 + c];
    for (int t = w; t < NCH; t += 4) {
      float v = chunkS[(g * NCH + t) * 64 + c];
      sa += v;
      if (t < ch) sp += v;
    }
    subP[w][c] = pp; subS[w][c] = sp; sall[w][c] = sa;
  }

  float offPw, offSw, totSw;
  {
    float w1 = chunkPw[g * NCH + c];
    float w2 = chunkPw[g * NCH + 64 + c];
    float pwo = (c < ch ? w1 : 0.f) + (c + 64 < ch ? w2 : 0.f);
    float u1 = chunkSw[g * NCH + c];
    float u2 = chunkSw[g * NCH + 64 + c];
    float swo = (c < ch ? u1 : 0.f) + (c + 64 < ch ? u2 : 0.f);
    float stw = u1 + u2;
    #pragma unroll
    for (int off = 1; off < 64; off <<= 1) {
      pwo += __shfl_xor(pwo, off);
      swo += __shfl_xor(swo, off);
      stw += __shfl_xor(stw, off);
    }
    offPw = pwo; offSw = swo; totSw = stw;
  }
  __syncthreads();

  const float offP = subP[0][c] + subP[1][c] + subP[2][c] + subP[3][c];
  const float offS = subS[0][c] + subS[1][c] + subS[2][c] + subS[3][c];
  const float totS = sall[0][c] + sall[1][c] + sall[2][c] + sall[3][c];

  // --- phase 4: row range via 64-ary ballot searches (2 dependent loads each, not 12) ---
  const float* ts = tsort + gNN;
  int rlo, rhi;
  {
    const float p1 = ts[c * 64 + 63];          // shared probe for both searches
    if (ch == 0) rlo = 0;
    else {
      const float blo = dsort[gNN + ch * CH];
      unsigned long long m1 = __ballot(p1 < blo);
      int blk = __popcll(m1);
      if (blk == 64) rlo = NN;
      else {
        float p2 = ts[blk * 64 + c];
        unsigned long long m2 = __ballot(p2 < blo);
        rlo = blk * 64 + __popcll(m2);
      }
    }
    if (ch == NCH - 1) rhi = NN;
    else {
      const float bhi = dsort[gNN + (ch + 1) * CH];
      unsigned long long m1 = __ballot(p1 < bhi);
      int blk = __popcll(m1);
      if (blk == 64) rhi = NN;
      else {
        float p2 = ts[blk * 64 + c];
        unsigned long long m2 = __ballot(p2 < bhi);
        rhi = blk * 64 + __popcll(m2);
      }
    }
  }

  const float myd = (c < 32) ? dsort[gNN + ch * CH + c] : __int_as_float(0x7f800000);
  const float biasv = bias[h64 + c];

  // --- phase 5: serve rows ---
  for (int r = rlo + w; r < rhi; r += 4) {
    const float t = ts[r];
    const int i = tperm[gNN + r];
    const int mloc = __popcll(__ballot(myd <= t));
    const float numB = PPloc[mloc][c] + offP;
    const float denB = ppwLoc[mloc] + offPw;
    const float numA = totS - (PSloc[mloc][c] + offS);
    const float denA = totSw - (pswLoc[mloc] + offSw);
    const float si = -t;
    const float sdm = si + dmax;
    const float mx = sdm > 0.f ? sdm : 0.2f * sdm;
    const float alpha = __expf(sdm - mx);
    const float beta = __expf(0.2f * sdm - mx);
    const float den = alpha * denA + beta * denB;
    float val = (alpha * numA + beta * numB) / den + biasv;
    float o = val > 0.f ? val : expm1f(val);
    out[(bNN + i) * NF + h64 + c] = o;
  }
}

extern "C" void kernel_launch(void* const* d_in, const int* in_sizes, int n_in,
                              void* d_out, int out_size, void* d_ws, size_t ws_size,
                              hipStream_t stream) {
  const float* X = (const float*)d_in[0];       // [2,4096,128]
  const float* W = (const float*)d_in[1];       // [128,256]
  const float* a_src = (const float*)d_in[2];   // [4,64,1]
  const float* a_dst = (const float*)d_in[3];   // [4,64,1]
  const float* bias = (const float*)d_in[4];    // [256]
  float* out = (float*)d_out;                   // [2,4096,256]

  float* ws = (float*)d_ws;
  float* s_arr = ws;                        // 8*4096
  float* d_arr = s_arr + NG * NN;           // 8*4096
  float* dsort = d_arr + NG * NN;           // 8*4096
  int* dperm = (int*)(dsort + NG * NN);     // 8*4096
  float* tsort = (float*)(dperm + NG * NN); // 8*4096
  int* tperm = (int*)(tsort + NG * NN);     // 8*4096
  float* chunkP = (float*)(tperm + NG * NN);    // 8*128*64
  float* chunkS = chunkP + NG * NCH * 64;
  float* chunkPw = chunkS + NG * NCH * 64;      // 8*128
  float* chunkSw = chunkPw + NG * NCH;
  __half* Hmat = (__half*)(chunkSw + NG * NCH); // 2*4096*256 halves (4 MB)

  k_gemm<<<dim3(128, 4), 256, 0, stream>>>(X, W, a_src, a_dst, Hmat, s_arr, d_arr);
  k_sort<<<2 * NG, 512, 0, stream>>>(d_arr, s_arr, dsort, dperm, tsort, tperm);
  k_part<<<dim3(NCH, NG), 256, 0, stream>>>(Hmat, dsort, dperm, chunkP, chunkS, chunkPw, chunkSw);
  k_serve<<<NG * NCH, 256, 0, stream>>>(Hmat, dsort, dperm, tsort, tperm,
                                        chunkP, chunkS, chunkPw, chunkSw, bias, out);
}